// Round 1
// baseline (572.928 us; speedup 1.0000x reference)
//
#include <hip/hip_runtime.h>
#include <hip/hip_bf16.h>

// Problem constants
#define BB 8
#define NN 128
#define CC 256
#define HFD 160
#define WFD 160
#define SS 7
#define REGION_OUT_ELEMS (8*128*256*49)   // 12,845,056

// ---------------------------------------------------------------------------
// K0: transpose proj_w [o][c] -> WT [c][o]  (256x256, trivial)
// ---------------------------------------------------------------------------
__global__ __launch_bounds__(256) void k0_transpose_w(const float* __restrict__ W,
                                                      float* __restrict__ WT) {
    int o = blockIdx.x;
    int c = threadIdx.x;
    WT[c * CC + o] = W[o * CC + c];
}

// ---------------------------------------------------------------------------
// K1: fused transpose + row-cumsum.
//   in : fm[b][c][h][w]   (w fastest)
//   out: R[b][h][w][c]    (c fastest), R = cumsum of fm along w
// One WG per (b, h, c-quarter of 64 channels). LDS tile 64x161 (pad +1).
// ---------------------------------------------------------------------------
__global__ __launch_bounds__(256) void k1_rowsum_transpose(const float* __restrict__ fm,
                                                           float* __restrict__ R) {
    int bid = blockIdx.x;            // ((b*160)+h)*4 + cq
    int cq  = bid & 3;
    int bh  = bid >> 2;
    int h   = bh % HFD;
    int b   = bh / HFD;
    int c0  = cq * 64;
    int t   = threadIdx.x;

    __shared__ float tile[64][161];
    __shared__ float segsum[64][5];

    // load: 64 channels x 160 w, mostly-coalesced rows
    #pragma unroll
    for (int it = 0; it < 40; ++it) {
        int idx = it * 256 + t;              // 0..10239
        int c_l = idx / 160;
        int w   = idx - c_l * 160;
        tile[c_l][w] = fm[(((size_t)(b * CC + c0 + c_l)) * HFD + h) * WFD + w];
    }
    __syncthreads();

    // 4-segment parallel row scan (seg = 40 elements)
    int seg = t >> 6;        // 0..3
    int row = t & 63;        // 0..63
    {
        float s = 0.f;
        int w0 = seg * 40;
        #pragma unroll 8
        for (int k = 0; k < 40; ++k) {
            s += tile[row][w0 + k];
            tile[row][w0 + k] = s;
        }
        segsum[row][seg] = s;
    }
    __syncthreads();
    if (t < 64) {
        float a0 = segsum[t][0];
        float a1 = a0 + segsum[t][1];
        float a2 = a1 + segsum[t][2];
        segsum[t][1] = a0;
        segsum[t][2] = a1;
        segsum[t][3] = a2;
    }
    __syncthreads();
    if (seg > 0) {
        float off = segsum[row][seg];
        int w0 = seg * 40;
        #pragma unroll 8
        for (int k = 0; k < 40; ++k) tile[row][w0 + k] += off;
    }
    __syncthreads();

    // write transposed: R[b][h][w][c0+c_l], coalesced in c
    size_t obase = (((size_t)b * HFD + h) * WFD) * CC + c0;
    #pragma unroll
    for (int it = 0; it < 40; ++it) {
        int idx = it * 256 + t;
        int w   = idx >> 6;       // 0..159
        int c_l = idx & 63;
        R[obase + (size_t)w * CC + c_l] = tile[c_l][w];
    }
}

// ---------------------------------------------------------------------------
// K2: in-place column cumsum along h in c-fastest layout.
// One WG per (b, w); lanes = c; serial over h with running register sum.
// ---------------------------------------------------------------------------
__global__ __launch_bounds__(256) void k2_colsum(float* __restrict__ I) {
    int w = blockIdx.x % WFD;
    int b = blockIdx.x / WFD;
    int c = threadIdx.x;
    size_t base   = (((size_t)b * HFD) * WFD + w) * CC + c;   // h = 0
    const size_t stride = (size_t)WFD * CC;                   // per-h stride
    float s = 0.f;
    #pragma unroll 8
    for (int h = 0; h < HFD; ++h) {
        float v = I[base + (size_t)h * stride];
        s += v;
        I[base + (size_t)h * stride] = s;
    }
}

// ---------------------------------------------------------------------------
// K3: per-(b,n): gather 49 box sums from integral image -> pooled means in LDS,
// then fp32 GEMM: out[bn][o][cell] = sum_c WT[c][o] * pooled[c][cell] + bias[o].
// Thread tile: 8 o x 7 cells (t<224). Also writes area_ratios.
// ---------------------------------------------------------------------------
__global__ __launch_bounds__(256) void k3_gather_gemm(
        const float* __restrict__ I, const float* __restrict__ WT,
        const float* __restrict__ bias, const float* __restrict__ bboxes,
        const int* __restrict__ ih_p, const int* __restrict__ iw_p,
        float* __restrict__ out) {
    int bn = blockIdx.x;         // b*128 + n
    int b  = bn >> 7;
    int t  = threadIdx.x;

    __shared__ __align__(16) float pooledT[CC][60];

    float bx1 = bboxes[bn * 4 + 0];
    float by1 = bboxes[bn * 4 + 1];
    float bx2 = bboxes[bn * 4 + 2];
    float by2 = bboxes[bn * 4 + 3];
    float sx = (float)WFD / (float)iw_p[0];
    float sy = (float)HFD / (float)ih_p[0];

    int x1 = min(max((int)floorf(bx1 * sx), 0), WFD - 1);
    int y1 = min(max((int)floorf(by1 * sy), 0), HFD - 1);
    int x2 = min(max((int)floorf(bx2 * sx), x1 + 1), WFD);
    int y2 = min(max((int)floorf(by2 * sy), y1 + 1), HFD);
    int Lx = x2 - x1, Ly = y2 - y1;

    int rs[SS], re[SS], cs[SS], ce[SS];
    #pragma unroll
    for (int i = 0; i < SS; ++i) {
        rs[i] = y1 + (i * Ly) / SS;
        re[i] = y1 + ((i + 1) * Ly + SS - 1) / SS;
        cs[i] = x1 + (i * Lx) / SS;
        ce[i] = x1 + ((i + 1) * Lx + SS - 1) / SS;
    }

    // gather phase: c = t, coalesced 256B-per-wave corner reads
    {
        const int c = t;
        const size_t Ib = (size_t)b * HFD * WFD * CC;
        #pragma unroll
        for (int i = 0; i < SS; ++i) {
            int r0 = rs[i] - 1, r1 = re[i] - 1;
            float rh = (float)(re[i] - rs[i]);
            #pragma unroll
            for (int j = 0; j < SS; ++j) {
                int c0 = cs[j] - 1, c1 = ce[j] - 1;
                float br = I[Ib + ((size_t)(r1 * WFD + c1)) * CC + c];
                float tr = (r0 >= 0) ? I[Ib + ((size_t)(r0 * WFD + c1)) * CC + c] : 0.f;
                float bl = (c0 >= 0) ? I[Ib + ((size_t)(r1 * WFD + c0)) * CC + c] : 0.f;
                float tl = (r0 >= 0 && c0 >= 0) ? I[Ib + ((size_t)(r0 * WFD + c0)) * CC + c] : 0.f;
                float cnt = rh * (float)(ce[j] - cs[j]);
                pooledT[c][i * 8 + j] = (br - tr - bl + tl) / cnt;
            }
        }
    }
    __syncthreads();

    // GEMM phase: 224 threads, thread = (cg 0..6, og 0..31): 8 o x 7 cells
    if (t < 224) {
        int og = t & 31;
        int cg = t >> 5;
        float acc[56];
        #pragma unroll
        for (int q = 0; q < 56; ++q) acc[q] = 0.f;

        #pragma unroll 2
        for (int cc = 0; cc < CC; ++cc) {
            float4 w0 = *(const float4*)(WT + cc * CC + og * 8);
            float4 w1 = *(const float4*)(WT + cc * CC + og * 8 + 4);
            float4 p0 = *(const float4*)(&pooledT[cc][cg * 8]);
            float4 p1 = *(const float4*)(&pooledT[cc][cg * 8 + 4]);
            float wv[8] = {w0.x, w0.y, w0.z, w0.w, w1.x, w1.y, w1.z, w1.w};
            float pv[7] = {p0.x, p0.y, p0.z, p0.w, p1.x, p1.y, p1.z};
            #pragma unroll
            for (int k = 0; k < 8; ++k)
                #pragma unroll
                for (int kk = 0; kk < 7; ++kk)
                    acc[k * 7 + kk] += wv[k] * pv[kk];
        }

        size_t ob = (size_t)bn * CC * 49;
        #pragma unroll
        for (int k = 0; k < 8; ++k) {
            int o = og * 8 + k;
            float bv = bias[o];
            #pragma unroll
            for (int kk = 0; kk < 7; ++kk) {
                out[ob + (size_t)o * 49 + cg * 7 + kk] = acc[k * 7 + kk] + bv;
            }
        }
    }

    if (t == 0) {
        out[REGION_OUT_ELEMS + bn] = (bx2 - bx1) * (by2 - by1);
    }
}

// ---------------------------------------------------------------------------
extern "C" void kernel_launch(void* const* d_in, const int* in_sizes, int n_in,
                              void* d_out, int out_size, void* d_ws, size_t ws_size,
                              hipStream_t stream) {
    const float* fm     = (const float*)d_in[0];
    const float* bboxes = (const float*)d_in[1];
    const float* W      = (const float*)d_in[2];
    const float* bias   = (const float*)d_in[3];
    const int*   ih     = (const int*)d_in[4];
    const int*   iw     = (const int*)d_in[5];
    float* out = (float*)d_out;

    float* WT = (float*)d_ws;                              // 256*256 floats
    float* I  = (float*)((char*)d_ws + (size_t)CC * CC * 4); // integral image, c-fastest

    k0_transpose_w<<<CC, 256, 0, stream>>>(W, WT);
    k1_rowsum_transpose<<<BB * HFD * 4, 256, 0, stream>>>(fm, I);
    k2_colsum<<<BB * WFD, 256, 0, stream>>>(I);
    k3_gather_gemm<<<BB * NN, 256, 0, stream>>>(I, WT, bias, bboxes, ih, iw, out);
}

// Round 2
// 461.970 us; speedup vs baseline: 1.2402x; 1.2402x over previous
//
#include <hip/hip_runtime.h>
#include <hip/hip_bf16.h>

// Problem constants
#define BB 8
#define NN 128
#define CC 256
#define HFD 160
#define WFD 160
#define SS 7
#define REGION_OUT_ELEMS (8*128*256*49)   // 12,845,056

typedef short short8 __attribute__((ext_vector_type(8)));
typedef float f32x4  __attribute__((ext_vector_type(4)));

// ---------------------------------------------------------------------------
// K0: convert proj_w [o][c] fp32 -> bf16, same row-major layout (A-operand
// friendly: MFMA A-frag reads 8 contiguous c at fixed o).
// ---------------------------------------------------------------------------
__global__ __launch_bounds__(256) void k0_convert_w(const float* __restrict__ W,
                                                    __hip_bfloat16* __restrict__ Wb) {
    int o = blockIdx.x;
    int c = threadIdx.x;
    Wb[o * CC + c] = __float2bfloat16(W[o * CC + c]);
}

// ---------------------------------------------------------------------------
// K1: fused transpose + row-cumsum.
//   in : fm[b][c][h][w]   (w fastest)
//   out: R[b][h][w][c]    (c fastest), R = cumsum of fm along w
// One WG per (b, h, c-quarter of 64 channels). LDS tile 64x161.
// Stride 161 == 1 (mod 32): transpose-phase column reads are 2-way (free).
// float4 global loads and stores.
// ---------------------------------------------------------------------------
__global__ __launch_bounds__(256) void k1_rowsum_transpose(const float* __restrict__ fm,
                                                           float* __restrict__ R) {
    int bid = blockIdx.x;            // ((b*160)+h)*4 + cq
    int cq  = bid & 3;
    int bh  = bid >> 2;
    int h   = bh % HFD;
    int b   = bh / HFD;
    int c0  = cq * 64;
    int t   = threadIdx.x;

    __shared__ float tile[64][161];
    __shared__ float segsum[64][5];

    // load: 2560 float4 (64 channels x 160 w), coalesced
    #pragma unroll
    for (int it = 0; it < 10; ++it) {
        int vid = it * 256 + t;              // 0..2559
        int c_l = vid / 40;
        int wq  = vid - c_l * 40;            // float4 index within row
        float4 v = *(const float4*)(fm + (((size_t)(b * CC + c0 + c_l)) * HFD + h) * WFD + wq * 4);
        tile[c_l][wq * 4 + 0] = v.x;
        tile[c_l][wq * 4 + 1] = v.y;
        tile[c_l][wq * 4 + 2] = v.z;
        tile[c_l][wq * 4 + 3] = v.w;
    }
    __syncthreads();

    // 4-segment parallel row scan (seg = 40 elements)
    int seg = t >> 6;        // 0..3
    int row = t & 63;        // 0..63
    {
        float s = 0.f;
        int w0 = seg * 40;
        #pragma unroll 8
        for (int k = 0; k < 40; ++k) {
            s += tile[row][w0 + k];
            tile[row][w0 + k] = s;
        }
        segsum[row][seg] = s;
    }
    __syncthreads();
    if (t < 64) {
        float a0 = segsum[t][0];
        float a1 = a0 + segsum[t][1];
        float a2 = a1 + segsum[t][2];
        segsum[t][1] = a0;
        segsum[t][2] = a1;
        segsum[t][3] = a2;
    }
    __syncthreads();
    if (seg > 0) {
        float off = segsum[row][seg];
        int w0 = seg * 40;
        #pragma unroll 8
        for (int k = 0; k < 40; ++k) tile[row][w0 + k] += off;
    }
    __syncthreads();

    // write transposed: R[b][h][w][c0 + 4*cg .. +3], float4 stores, coalesced in c
    size_t obase = (((size_t)b * HFD + h) * WFD) * CC + c0;
    #pragma unroll
    for (int it = 0; it < 10; ++it) {
        int vid = it * 256 + t;
        int w   = vid >> 4;        // 0..159
        int cg  = vid & 15;        // c = 4*cg
        float4 o;
        o.x = tile[cg * 4 + 0][w];
        o.y = tile[cg * 4 + 1][w];
        o.z = tile[cg * 4 + 2][w];
        o.w = tile[cg * 4 + 3][w];
        *(float4*)(R + obase + (size_t)w * CC + cg * 4) = o;
    }
}

// ---------------------------------------------------------------------------
// K2: in-place column cumsum along h in c-fastest layout.
// One 64-thread WG per (b, w); thread owns 4 channels (float4 RMW).
// ---------------------------------------------------------------------------
__global__ __launch_bounds__(64) void k2_colsum(float* __restrict__ I) {
    int w = blockIdx.x % WFD;
    int b = blockIdx.x / WFD;
    int c4 = threadIdx.x * 4;
    float* p = I + (((size_t)b * HFD) * WFD + w) * CC + c4;   // h = 0
    const size_t stride = (size_t)WFD * CC;                   // per-h stride (floats)
    float sx = 0.f, sy = 0.f, sz = 0.f, sw = 0.f;
    #pragma unroll 8
    for (int h = 0; h < HFD; ++h) {
        float4 v = *(float4*)(p + (size_t)h * stride);
        sx += v.x; sy += v.y; sz += v.z; sw += v.w;
        float4 s = {sx, sy, sz, sw};
        *(float4*)(p + (size_t)h * stride) = s;
    }
}

// ---------------------------------------------------------------------------
// K3: per-(b,n): gather 49 box means from integral image (fp32), convert to
// bf16 in LDS (B-operand layout: P[cell][c], row stride 264), then MFMA GEMM:
// out[bn][o][cell] = sum_c W[o][c] * P[c][cell] + bias[o].
// M=256 (o), N=64 (49 cells + pad), K=256. Wave w owns o-range [64w,64w+64).
// ---------------------------------------------------------------------------
#define PB_STRIDE 264   // bf16 elems; 528 B row: b128 reads land 2-way (free)

__global__ __launch_bounds__(256) void k3_gather_gemm(
        const float* __restrict__ I, const __hip_bfloat16* __restrict__ Wb,
        const float* __restrict__ bias, const float* __restrict__ bboxes,
        const int* __restrict__ ih_p, const int* __restrict__ iw_p,
        float* __restrict__ out) {
    int bn = blockIdx.x;         // b*128 + n
    int b  = bn >> 7;
    int t  = threadIdx.x;

    __shared__ __hip_bfloat16 Pb[64 * PB_STRIDE];   // 33 KB

    float bx1 = bboxes[bn * 4 + 0];
    float by1 = bboxes[bn * 4 + 1];
    float bx2 = bboxes[bn * 4 + 2];
    float by2 = bboxes[bn * 4 + 3];
    float sx = (float)WFD / (float)iw_p[0];
    float sy = (float)HFD / (float)ih_p[0];

    int x1 = min(max((int)floorf(bx1 * sx), 0), WFD - 1);
    int y1 = min(max((int)floorf(by1 * sy), 0), HFD - 1);
    int x2 = min(max((int)floorf(bx2 * sx), x1 + 1), WFD);
    int y2 = min(max((int)floorf(by2 * sy), y1 + 1), HFD);
    int Lx = x2 - x1, Ly = y2 - y1;

    int rs[SS], re[SS], cs[SS], ce[SS];
    #pragma unroll
    for (int i = 0; i < SS; ++i) {
        rs[i] = y1 + (i * Ly) / SS;
        re[i] = y1 + ((i + 1) * Ly + SS - 1) / SS;
        cs[i] = x1 + (i * Lx) / SS;
        ce[i] = x1 + ((i + 1) * Lx + SS - 1) / SS;
    }

    // zero the pad cells (rows 49..63 of Pb)
    #pragma unroll
    for (int r = 49; r < 64; ++r) Pb[r * PB_STRIDE + t] = __float2bfloat16(0.f);

    // gather phase: lane = c, coalesced 1KB-per-block corner reads
    {
        const int c = t;
        const size_t Ib = (size_t)b * HFD * WFD * CC;
        #pragma unroll
        for (int i = 0; i < SS; ++i) {
            int r0 = rs[i] - 1, r1 = re[i] - 1;
            float rh = (float)(re[i] - rs[i]);
            #pragma unroll
            for (int j = 0; j < SS; ++j) {
                int c0 = cs[j] - 1, c1 = ce[j] - 1;
                float br = I[Ib + ((size_t)(r1 * WFD + c1)) * CC + c];
                float tr = (r0 >= 0) ? I[Ib + ((size_t)(r0 * WFD + c1)) * CC + c] : 0.f;
                float bl = (c0 >= 0) ? I[Ib + ((size_t)(r1 * WFD + c0)) * CC + c] : 0.f;
                float tl = (r0 >= 0 && c0 >= 0) ? I[Ib + ((size_t)(r0 * WFD + c0)) * CC + c] : 0.f;
                float cnt = rh * (float)(ce[j] - cs[j]);
                Pb[(i * SS + j) * PB_STRIDE + c] = __float2bfloat16((br - tr - bl + tl) / cnt);
            }
        }
    }
    __syncthreads();

    // MFMA GEMM phase: wave wv handles o in [wv*64, wv*64+64)
    {
        const int lane = t & 63;
        const int wv   = t >> 6;
        const int ln   = lane & 15;
        const int quad = lane >> 4;
        const int ob0  = wv * 64;

        f32x4 z = {0.f, 0.f, 0.f, 0.f};
        f32x4 acc[4][4];
        #pragma unroll
        for (int mt = 0; mt < 4; ++mt)
            #pragma unroll
            for (int nt = 0; nt < 4; ++nt) acc[mt][nt] = z;

        #pragma unroll
        for (int k0 = 0; k0 < CC; k0 += 32) {
            short8 a[4], bf[4];
            #pragma unroll
            for (int mt = 0; mt < 4; ++mt)
                a[mt] = *(const short8*)((const short*)Wb + (ob0 + mt * 16 + ln) * CC + k0 + quad * 8);
            #pragma unroll
            for (int nt = 0; nt < 4; ++nt)
                bf[nt] = *(const short8*)((const short*)Pb + (nt * 16 + ln) * PB_STRIDE + k0 + quad * 8);
            #pragma unroll
            for (int mt = 0; mt < 4; ++mt)
                #pragma unroll
                for (int nt = 0; nt < 4; ++nt)
                    acc[mt][nt] = __builtin_amdgcn_mfma_f32_16x16x32_bf16(a[mt], bf[nt], acc[mt][nt], 0, 0, 0);
        }

        // epilogue: D layout col(cell)=lane&15, row(o)=quad*4+reg
        size_t obase = (size_t)bn * CC * 49;
        #pragma unroll
        for (int mt = 0; mt < 4; ++mt) {
            f32x4 bv = *(const f32x4*)(bias + ob0 + mt * 16 + quad * 4);
            #pragma unroll
            for (int nt = 0; nt < 4; ++nt) {
                int cell = nt * 16 + ln;
                if (cell < 49) {
                    #pragma unroll
                    for (int reg = 0; reg < 4; ++reg) {
                        int o = ob0 + mt * 16 + quad * 4 + reg;
                        out[obase + (size_t)o * 49 + cell] = acc[mt][nt][reg] + bv[reg];
                    }
                }
            }
        }
    }

    if (t == 0) {
        out[REGION_OUT_ELEMS + bn] = (bx2 - bx1) * (by2 - by1);
    }
}

// ---------------------------------------------------------------------------
extern "C" void kernel_launch(void* const* d_in, const int* in_sizes, int n_in,
                              void* d_out, int out_size, void* d_ws, size_t ws_size,
                              hipStream_t stream) {
    const float* fm     = (const float*)d_in[0];
    const float* bboxes = (const float*)d_in[1];
    const float* W      = (const float*)d_in[2];
    const float* bias   = (const float*)d_in[3];
    const int*   ih     = (const int*)d_in[4];
    const int*   iw     = (const int*)d_in[5];
    float* out = (float*)d_out;

    __hip_bfloat16* Wb = (__hip_bfloat16*)d_ws;                 // 256*256 bf16 = 128 KB
    float* I = (float*)((char*)d_ws + (size_t)CC * CC * 2 + 256); // integral image, c-fastest
    // keep I 1KB-aligned
    I = (float*)(((uintptr_t)I + 1023) & ~(uintptr_t)1023);

    k0_convert_w<<<CC, 256, 0, stream>>>(W, Wb);
    k1_rowsum_transpose<<<BB * HFD * 4, 256, 0, stream>>>(fm, I);
    k2_colsum<<<BB * WFD, 64, 0, stream>>>(I);
    k3_gather_gemm<<<BB * NN, 256, 0, stream>>>(I, Wb, bias, bboxes, ih, iw, out);
}